// Round 9
// baseline (320.746 us; speedup 1.0000x reference)
//
#include <hip/hip_runtime.h>

// GlobalChannelAttention: B=16, C=256, H*W=4096
//
// Pipeline (TN-form GEMMs: C[M,N] = sum_k A[m][k]*B[n][k], K contiguous):
//   1. prep_w: w1 -> W1Th (bf16 transposed), w2/w3 -> hi/lo bf16, zero xsum
//   2. gram: G[b] = X X^T from raw x f32 (hi/lo in SEPARATE LDS slabs, 3
//      MFMAs hh+hl+lh). HALF-M blocks: grid 16b x 16splits x 2mhalf.
//      Load-issue point AFTER stage8 (R19): loads outstanding across
//      barrier+fragment-reads+MFMA of the next step (~full cycle).
//   3. reduce_bias: sum 16 Gp partials -> Gh/Gl bf16 + bias S2/S3 (fused).
//      T3 = W3*G (G symmetric); Lt = T3*W2^T (EPI=3: epilogue computes
//      per-tile biased max/sumexp partials -> softmax pass1 eliminated).
//   4. softmax pass3: combine 16 tile partials + write WT bf16 + fused
//      bb[d] = sum_c WT[d][c]*b1[c].
//   5. Mh = WT*W1T (bf16); out = Mh*X^T + bb, 256x128 tiles, 512 thr.
//
// Precision: logit chain bf16 hi/lo x3 (err ~2^-17 rel); out chain plain bf16.
// R7: atomic-f32 Gram epilogue regressed (16-way same-address L2 contention).
// R8: k-interleaved hi/lo loses hi*lo cross terms -> accuracy fail.
// R9: 128-VGPR acc forced fragment rematerialization -> LDS-read bound.
// R10: separate xsum_kernel re-read 64MB of x -- folded back into gram.
// R11: gram 16 k-splits, 64KiB LDS XOR-swizzle, cvt_pk staging. 46->41us,
//     0 bank conflicts (verified R5).
// R12/R13: launch_bounds(512,4) = 4 BLOCKS/CU -> 64-VGPR cap -> spill.
// R14: (512,2): spill gone; lB-write conflicts found.
// R15: gemm_out gload_lds dbuf A + conflict-free lB; left top-5.
// R16: gemm_small full-panel LDS single-barrier; left top-5.
// R17/R18: pass1 fused into gemm#2 epilogue (-4us total -> launch cost
//     ~4us each); gram k-stagger NEUTRAL (FETCH still 65MB, dedup held).
// R19 (this round): gram load-issue moved AFTER stage8 -- loads in flight
//     across barrier+frag-reads+next MFMA instead of only the MFMA phase
//     (duty ~55% -> ~95%, zero extra VGPR; 2-deep prefetch would need
//     144 regs/wave and drop to 1 block/CU). reduce_g+bias_prep merged
//     into one 1040-block kernel (-1 launch).

typedef unsigned short u16;
typedef __attribute__((ext_vector_type(8))) short short8;
typedef __attribute__((ext_vector_type(4))) float floatx4;

__device__ __forceinline__ u16 f2b(float f) {
  union { float f; unsigned int u; } v; v.f = f;
  unsigned int u = v.u;
  return (u16)((u + 0x7fffu + ((u >> 16) & 1u)) >> 16);  // RNE
}
__device__ __forceinline__ float b2f(u16 h) {
  union { unsigned int u; float f; } v; v.u = ((unsigned int)h) << 16;
  return v.f;
}
// HW packed f32->bf16 (RNE), lo -> bits[15:0], hi -> bits[31:16].
__device__ __forceinline__ unsigned int cvt_pk_bf16(float lo, float hi) {
  unsigned int r;
  asm("v_cvt_pk_bf16_f32 %0, %1, %2" : "=v"(r) : "v"(lo), "v"(hi));
  return r;
}
// async global->LDS, 16B per lane. LDS dest = wave-uniform base + lane*16.
__device__ __forceinline__ void gload_lds16(const u16* g, u16* l) {
  __builtin_amdgcn_global_load_lds(
      (const __attribute__((address_space(1))) unsigned int*)(const void*)g,
      (__attribute__((address_space(3))) unsigned int*)(void*)l, 16, 0, 0);
}

// ------- merged W prep: transpose w1 + split w2/w3 + zero xsum -------------
__global__ __launch_bounds__(256) void prep_w_kernel(
    const float* __restrict__ w1, const float* __restrict__ w2, const float* __restrict__ w3,
    u16* __restrict__ W1Th, u16* __restrict__ W2h, u16* __restrict__ W2l,
    u16* __restrict__ W3h, u16* __restrict__ W3l, float* __restrict__ xsum) {
  const int blk = blockIdx.x, t = threadIdx.x;
  if (blk == 576) {  // zero xsum (16*256 f32)
#pragma unroll
    for (int i = 0; i < 16; ++i) xsum[t + i * 256] = 0.f;
    return;
  }
  if (blk < 64) {  // W1Th[e][c] = w1[c][e]
    __shared__ float tile[32][33];
    const int e0 = (blk & 7) * 32, c0 = (blk >> 3) * 32;
    const int tx = t & 31, ty = t >> 5;
#pragma unroll
    for (int i = 0; i < 4; ++i)
      tile[ty + i * 8][tx] = w1[(c0 + ty + i * 8) * 256 + e0 + tx];
    __syncthreads();
#pragma unroll
    for (int i = 0; i < 4; ++i)
      W1Th[(e0 + ty + i * 8) * 256 + c0 + tx] = f2b(tile[tx][ty + i * 8]);
  } else {
    const int i = (blk - 64) * 256 + t;  // 0..131071
    const int e = i & 0xffff;
    const float f = (i >> 16) ? w3[e] : w2[e];
    u16 h = f2b(f);
    if (i >> 16) { W3h[e] = h; W3l[e] = f2b(f - b2f(h)); }
    else         { W2h[e] = h; W2l[e] = f2b(f - b2f(h)); }
  }
}

// ---- stage 8 f32 -> hi/lo bf16 LDS (one uint4 each) + running sum --------
__device__ __forceinline__ void stage8(const float4 a, const float4 b,
                                       u16* dH, u16* dL, float& xa) {
  const float f[8] = {a.x, a.y, a.z, a.w, b.x, b.y, b.z, b.w};
  union { unsigned int w[4]; uint4 q; } uh, ul;
#pragma unroll
  for (int i = 0; i < 4; ++i) {
    const unsigned int h = cvt_pk_bf16(f[2 * i], f[2 * i + 1]);
    uh.w[i] = h;
    union { unsigned int u; float ff; } h0, h1;
    h0.u = h << 16;            // bf16 of f[2i] back to f32
    h1.u = h & 0xffff0000u;    // bf16 of f[2i+1] back to f32
    ul.w[i] = cvt_pk_bf16(f[2 * i] - h0.ff, f[2 * i + 1] - h1.ff);
    xa += f[2 * i] + f[2 * i + 1];
  }
  *(uint4*)dH = uh.q;
  *(uint4*)dL = ul.q;
}

// ---------------- Gram: half-M blocks, hoisted fragments -------------------
// grid = 16b x 16s x 2mh. 512 thr / 8 waves, wave tile 64x64, k-chunk 256.
// LDS: row r = 64B = 4x16B slots; slot q ^ ((r>>1)&3); both phases bank-free
// (measured 0 conflicts). 64 KiB -> 2 blocks/CU. Loads for step kb+2 are
// issued AFTER stage8 of kb+1 (R19): register loads are NOT drained by
// __syncthreads (only LDS/global writes are), so they stay in flight across
// the barrier + fragment reads + the whole next MFMA phase.
__global__ __launch_bounds__(512, 4) void gram_kernel(
    const float* __restrict__ x, float* __restrict__ Gp, float* __restrict__ xsum) {
  __shared__ u16 lH[2][256 * 32], lL[2][256 * 32];  // 64 KB total
  const int b = blockIdx.x >> 5, s = (blockIdx.x >> 1) & 15, mh = blockIdx.x & 1;
  const float* Xb = x + (long)b * 1048576 + s * 256;
  const int t = threadIdx.x;
  const int lane = t & 63, wave = t >> 6;
  const int quad = lane >> 4, l16 = lane & 15;
  const int wml = (wave & 1) * 64 + mh * 128;  // A rows in slab
  const int wn = (wave >> 1) * 64;             // B rows
  const int r0 = t >> 2, qc = (t & 3) * 8;
  const int r1 = r0 + 128;                     // (r1>>1)&3 == (r0>>1)&3
  const int wq = (((t & 3) ^ ((r0 >> 1) & 3))) * 8;  // swizzled write slot
  const int rq = ((quad ^ ((l16 >> 1) & 3))) * 8;    // swizzled read slot
  const int ph = s & 7;  // k-step phase stagger
  floatx4 acc[4][4] = {};
  float xa0 = 0.f, xa1 = 0.f;  // per-row running sums (rows r0, r1)
  float4 p[4];
  {
    const long k0 = (long)(ph * 32);
    p[0] = *(const float4*)(Xb + (long)r0 * 4096 + k0 + qc);
    p[1] = *(const float4*)(Xb + (long)r0 * 4096 + k0 + qc + 4);
    p[2] = *(const float4*)(Xb + (long)r1 * 4096 + k0 + qc);
    p[3] = *(const float4*)(Xb + (long)r1 * 4096 + k0 + qc + 4);
  }
  stage8(p[0], p[1], lH[0] + r0 * 32 + wq, lL[0] + r0 * 32 + wq, xa0);
  stage8(p[2], p[3], lH[0] + r1 * 32 + wq, lL[0] + r1 * 32 + wq, xa1);
  {
    const long k1 = (long)(((1 + ph) & 7) * 32);
    p[0] = *(const float4*)(Xb + (long)r0 * 4096 + k1 + qc);
    p[1] = *(const float4*)(Xb + (long)r0 * 4096 + k1 + qc + 4);
    p[2] = *(const float4*)(Xb + (long)r1 * 4096 + k1 + qc);
    p[3] = *(const float4*)(Xb + (long)r1 * 4096 + k1 + qc + 4);
  }
  __syncthreads();
  for (int kb = 0; kb < 8; ++kb) {
    const int cur = kb & 1, nxt = cur ^ 1;
    const u16* cH = lH[cur];
    const u16* cL = lL[cur];
    short8 ah[4], al[4];
#pragma unroll
    for (int i = 0; i < 4; ++i) {
      ah[i] = *(const short8*)(cH + (wml + i * 16 + l16) * 32 + rq);
      al[i] = *(const short8*)(cL + (wml + i * 16 + l16) * 32 + rq);
    }
#pragma unroll
    for (int j = 0; j < 4; ++j) {
      const short8 bh = *(const short8*)(cH + (wn + j * 16 + l16) * 32 + rq);
      const short8 bl = *(const short8*)(cL + (wn + j * 16 + l16) * 32 + rq);
#pragma unroll
      for (int i = 0; i < 4; ++i) {
        acc[i][j] = __builtin_amdgcn_mfma_f32_16x16x32_bf16(ah[i], bh, acc[i][j], 0, 0, 0);
        acc[i][j] = __builtin_amdgcn_mfma_f32_16x16x32_bf16(ah[i], bl, acc[i][j], 0, 0, 0);
        acc[i][j] = __builtin_amdgcn_mfma_f32_16x16x32_bf16(al[i], bh, acc[i][j], 0, 0, 0);
      }
    }
    if (kb < 7) {
      // stage data for step kb+1 (loaded one step ago), then immediately
      // issue loads for step kb+2 so they ride out the barrier + next MFMA.
      stage8(p[0], p[1], lH[nxt] + r0 * 32 + wq, lL[nxt] + r0 * 32 + wq, xa0);
      stage8(p[2], p[3], lH[nxt] + r1 * 32 + wq, lL[nxt] + r1 * 32 + wq, xa1);
      if (kb < 6) {
        const long kk = (long)(((kb + 2 + ph) & 7) * 32);
        p[0] = *(const float4*)(Xb + (long)r0 * 4096 + kk + qc);
        p[1] = *(const float4*)(Xb + (long)r0 * 4096 + kk + qc + 4);
        p[2] = *(const float4*)(Xb + (long)r1 * 4096 + kk + qc);
        p[3] = *(const float4*)(Xb + (long)r1 * 4096 + kk + qc + 4);
      }
    }
    __syncthreads();
  }
  if (mh == 0) {
    float v = xa0;
    v += __shfl_xor(v, 1);
    v += __shfl_xor(v, 2);
    if ((t & 3) == 0) atomicAdd(&xsum[b * 256 + r0], v);
    v = xa1;
    v += __shfl_xor(v, 1);
    v += __shfl_xor(v, 2);
    if ((t & 3) == 0) atomicAdd(&xsum[b * 256 + r1], v);
  }
  float* G = Gp + ((long)b * 16 + s) * 65536;
#pragma unroll
  for (int i = 0; i < 4; ++i) {
    const int row0 = wml + i * 16 + quad * 4;
#pragma unroll
    for (int j = 0; j < 4; ++j) {
      const int col = wn + j * 16 + l16;
#pragma unroll
      for (int r = 0; r < 4; ++r)
        G[(long)(row0 + r) * 256 + col] = acc[i][j][r];
    }
  }
}

// -- fused: Gram split-K reduction (blocks 0..1023) + bias prep (1024..1039)
// reduce: 4 consecutive elems/thread, same i=0..15 order (bitwise-identical).
// bias: S2[b][a]=w2[a,:]·xsum[b], S3 likewise (one block per batch).
__global__ __launch_bounds__(256) void reduce_bias_kernel(
    const float* __restrict__ Gp, u16* __restrict__ Gh, u16* __restrict__ Gl,
    const float* __restrict__ w2, const float* __restrict__ w3,
    const float* __restrict__ xsum, float* __restrict__ S2, float* __restrict__ S3) {
  __shared__ float xs[256];
  const int t = threadIdx.x;
  if (blockIdx.x < 1024) {
    const long e = ((long)blockIdx.x * 256 + t) * 4;    // elem base
    const long base = ((e >> 16) << 20) + (e & 65535);  // b*16*65536 + idx
    float4 s = {0.f, 0.f, 0.f, 0.f};
#pragma unroll
    for (int i = 0; i < 16; ++i) {
      const float4 v = *(const float4*)(Gp + base + (long)i * 65536);
      s.x += v.x; s.y += v.y; s.z += v.z; s.w += v.w;
    }
    union { u16 h[4]; uint2 q; } oh, ol;
    const float sv[4] = {s.x, s.y, s.z, s.w};
#pragma unroll
    for (int c = 0; c < 4; ++c) {
      const u16 h = f2b(sv[c]);
      oh.h[c] = h;
      ol.h[c] = f2b(sv[c] - b2f(h));
    }
    *(uint2*)(Gh + e) = oh.q;
    *(uint2*)(Gl + e) = ol.q;
  } else {
    const int b = blockIdx.x - 1024;
    xs[t] = xsum[b * 256 + t];
    __syncthreads();
    float s2 = 0.f, s3 = 0.f;
#pragma unroll 4
    for (int c = 0; c < 256; ++c) {
      s2 += w2[t * 256 + c] * xs[c];
      s3 += w3[t * 256 + c] * xs[c];
    }
    S2[b * 256 + t] = s2;
    S3[b * 256 + t] = s3;
  }
}

// ------- small 256x256x256 TN GEMM: full-panel LDS, 64x64 tiles ------------
// Full A(64x256) + B(64x256) hi(/lo) panels staged ONCE into padded LDS
// ([64][264] u16, 528B row stride -> conflict-free), one barrier, then 8
// barrier-free k-steps. Grid 256 = 1 block/CU. EPI: 0=f32, 1=bf16 hi/lo,
// 2=bf16 hi, 3=f32 + fused softmax-pass1 stats (biased per-tile max/sumexp
// -> bm/bs[b*16+blk]; raw value still stored to outF).
template <bool X3, int EPI>
__global__ __launch_bounds__(256) void gemm_small(
    const u16* __restrict__ Ah, const u16* __restrict__ Al,
    const u16* __restrict__ Bh, const u16* __restrict__ Bl,
    long aBatch, long bBatch, long oBatch,
    float* __restrict__ outF, u16* __restrict__ outH, u16* __restrict__ outL,
    const float* __restrict__ S2, const float* __restrict__ S3,
    const float* __restrict__ b2v, const float* __restrict__ b3v,
    float* __restrict__ bm, float* __restrict__ bs) {
  constexpr int LW = 264;  // row stride in elems (528 B)
  __shared__ u16 smem[(X3 ? 4 : 2) * 64 * LW];
  __shared__ float rm[4], rs[4];  // EPI3 block-reduce scratch
  u16* lAh = smem;
  u16* lBh = smem + 64 * LW;
  u16* lAl = X3 ? (smem + 2 * 64 * LW) : nullptr;
  u16* lBl = X3 ? (smem + 3 * 64 * LW) : nullptr;
  const int b = blockIdx.z;
  const int tm = blockIdx.x & 3, tn = blockIdx.x >> 2;  // 4x4 tiles of 64
  const u16* Ahb = Ah + (long)b * aBatch + (long)tm * 64 * 256;
  const u16* Bhb = Bh + (long)b * bBatch + (long)tn * 64 * 256;
  const int t = threadIdx.x;
  const int lane = t & 63, wave = t >> 6;
  const int quad = lane >> 4, l16 = lane & 15;
  const int wm = (wave & 1) * 32, wn = (wave >> 1) * 32;
  const int r = t >> 2, c4 = t & 3;  // staging: row r, slots c4+4j (16B each)
  {
    uint4 tmp[8];
#pragma unroll
    for (int j = 0; j < 8; ++j)
      tmp[j] = *(const uint4*)(Ahb + (long)r * 256 + (c4 + 4 * j) * 8);
#pragma unroll
    for (int j = 0; j < 8; ++j)
      *(uint4*)(lAh + r * LW + (c4 + 4 * j) * 8) = tmp[j];
#pragma unroll
    for (int j = 0; j < 8; ++j)
      tmp[j] = *(const uint4*)(Bhb + (long)r * 256 + (c4 + 4 * j) * 8);
#pragma unroll
    for (int j = 0; j < 8; ++j)
      *(uint4*)(lBh + r * LW + (c4 + 4 * j) * 8) = tmp[j];
    if (X3) {
      const u16* Alb = Al + (long)b * aBatch + (long)tm * 64 * 256;
      const u16* Blb = Bl + (long)b * bBatch + (long)tn * 64 * 256;
#pragma unroll
      for (int j = 0; j < 8; ++j)
        tmp[j] = *(const uint4*)(Alb + (long)r * 256 + (c4 + 4 * j) * 8);
#pragma unroll
      for (int j = 0; j < 8; ++j)
        *(uint4*)(lAl + r * LW + (c4 + 4 * j) * 8) = tmp[j];
#pragma unroll
      for (int j = 0; j < 8; ++j)
        tmp[j] = *(const uint4*)(Blb + (long)r * 256 + (c4 + 4 * j) * 8);
#pragma unroll
      for (int j = 0; j < 8; ++j)
        *(uint4*)(lBl + r * LW + (c4 + 4 * j) * 8) = tmp[j];
    }
  }
  __syncthreads();  // the ONLY barrier in the GEMM body
  floatx4 acc[2][2] = {};
#pragma unroll
  for (int kk = 0; kk < 8; ++kk) {
    const int co = kk * 32 + quad * 8;
    short8 afh[2], bfh[2];
#pragma unroll
    for (int i = 0; i < 2; ++i) {
      afh[i] = *(const short8*)(lAh + (wm + i * 16 + l16) * LW + co);
      bfh[i] = *(const short8*)(lBh + (wn + i * 16 + l16) * LW + co);
    }
    if (X3) {
      short8 afl[2], bfl[2];
#pragma unroll
      for (int i = 0; i < 2; ++i) {
        afl[i] = *(const short8*)(lAl + (wm + i * 16 + l16) * LW + co);
        bfl[i] = *(const short8*)(lBl + (wn + i * 16 + l16) * LW + co);
      }
#pragma unroll
      for (int i = 0; i < 2; ++i)
#pragma unroll
        for (int j = 0; j < 2; ++j) {
          acc[i][j] = __builtin_amdgcn_mfma_f32_16x16x32_bf16(afh[i], bfh[j], acc[i][j], 0, 0, 0);
          acc[i][j] = __builtin_amdgcn_mfma_f32_16x16x32_bf16(afh[i], bfl[j], acc[i][j], 0, 0, 0);
          acc[i][j] = __builtin_amdgcn_mfma_f32_16x16x32_bf16(afl[i], bfh[j], acc[i][j], 0, 0, 0);
        }
    } else {
#pragma unroll
      for (int i = 0; i < 2; ++i)
#pragma unroll
        for (int j = 0; j < 2; ++j)
          acc[i][j] = __builtin_amdgcn_mfma_f32_16x16x32_bf16(afh[i], bfh[j], acc[i][j], 0, 0, 0);
    }
  }
  const long obase = (long)b * oBatch;
  if (EPI == 3) {
    // store raw Lt + fused pass1 stats on biased values
    float vals[2][2][4];
    float vmax = -3.4e38f;
#pragma unroll
    for (int i = 0; i < 2; ++i) {
      const int mb = tm * 64 + wm + i * 16 + quad * 4;
#pragma unroll
      for (int rr = 0; rr < 4; ++rr) {
        const int d = mb + rr;
        const float c1 = b3v[d];
        const float c0 = S3[b * 256 + d] + 4096.f * c1;
#pragma unroll
        for (int j = 0; j < 2; ++j) {
          const int a = tn * 64 + wn + j * 16 + l16;
          const float raw = acc[i][j][rr];
          const float vv = raw + b2v[a] * c0 + c1 * S2[b * 256 + a];
          vals[i][j][rr] = vv;
          vmax = fmaxf(vmax, vv);
          outF[obase + (long)d * 256 + a] = raw;
        }
      }
    }
    for (int o = 32; o; o >>= 1) vmax = fmaxf(vmax, __shfl_xor(vmax, o));
    if (lane == 0) rm[wave] = vmax;
    __syncthreads();
    const float bmax = fmaxf(fmaxf(rm[0], rm[1]), fmaxf(rm[2], rm[3]));
    float se = 0.f;
#pragma unroll
    for (int i = 0; i < 2; ++i)
#pragma unroll
      for (int j = 0; j < 2; ++j)
#pragma unroll
        for (int rr = 0; rr < 4; ++rr) se += __expf(vals[i][j][rr] - bmax);
    for (int o = 32; o; o >>= 1) se += __shfl_xor(se, o);
    if (lane == 0) rs[wave] = se;
    __syncthreads();
    if (t == 0) {
      bm[b * 16 + blockIdx.x] = bmax;
      bs[b * 16 + blockIdx.x] = rs[0] + rs[1] + rs[2] + rs[3];
    }
    return;
  }
#pragma unroll
  for (int i = 0; i < 2; ++i) {
    const int mb = tm * 64 + wm + i * 16 + quad * 4;
#pragma unroll
    for (int j = 0; j < 2; ++j) {
      const int n = tn * 64 + wn + j * 16 + l16;
#pragma unroll
      for (int rr = 0; rr < 4; ++rr) {
        const float v = acc[i][j][rr];
        const long idx = obase + (long)(mb + rr) * 256 + n;
        if (EPI == 0) {
          outF[idx] = v;
        } else if (EPI == 1) {
          u16 h = f2b(v);
          outH[idx] = h;
          outL[idx] = f2b(v - b2f(h));
        } else {
          outH[idx] = f2b(v);
        }
      }
    }
  }
}

// ------------- out = Mh * X^T + bb : 256x128 per block, 8 waves ------------
// A (Mh bf16): global_load_lds width-16, double-buffered, rows 64B (LR=32),
// XOR slot q^((r>>1)&3) applied to per-lane GLOBAL source col + read slot.
// B (x f32): 8 coalesced scalar dwords, cvt_pk pair-pack into lB (LR=40);
// lane t writes nl=(t&31)+32i (write phase conflict-free).
__global__ __launch_bounds__(512, 2) void gemm_out(
    const u16* __restrict__ Mh, const float* __restrict__ x,
    const float* __restrict__ bb, float* __restrict__ out) {
  __shared__ u16 lA[2][256 * 32];  // 2 x 16 KB
  __shared__ u16 lB[128 * 40];     // 10 KB
  const int b = blockIdx.z;
  const int tn = blockIdx.x;  // 0..31
  const u16* Ab = Mh + (long)b * 65536;
  const float* Xb = x + (long)b * 1048576 + tn * 128;
  const int t = threadIdx.x;
  const int lane = t & 63, wave = t >> 6;
  const int quad = lane >> 4, l16 = lane & 15;
  const int wm = (wave & 3) * 64;     // 4 m-waves
  const int wn = (wave >> 2) * 64;    // 2 n-waves
  const int erp = (t >> 5) * 2;       // e-row pair base 0..30
  const int n0 = t & 31;              // B col base (cols n0+32i)
  const int ra = t >> 2;              // A row
  const int sc = ((t & 3) ^ ((t >> 3) & 3)) * 8;   // pre-swizzled A src col
  const int rqA = (quad ^ ((l16 >> 1) & 3)) * 8;   // A read slot
  u16* wA0 = &lA[0][0] + wave * 16 * 32;           // wave-uniform LDS bases
  u16* wA1 = &lA[1][0] + wave * 16 * 32;
  floatx4 acc[4][4] = {};
  float pb[8];
  gload_lds16(Ab + (long)ra * 256 + sc, wA0);
  gload_lds16(Ab + (long)(ra + 128) * 256 + sc, wA0 + 128 * 32);
#pragma unroll
  for (int i = 0; i < 4; ++i) {
    pb[i]     = Xb[(long)erp * 4096 + n0 + 32 * i];
    pb[4 + i] = Xb[(long)(erp + 1) * 4096 + n0 + 32 * i];
  }
  for (int s = 0; s < 8; ++s) {
    const int kk = s * 32;
    const u16* curA = lA[s & 1];
    __syncthreads();  // drains gloads into buf[s&1] + pb loads (vmcnt 0)
#pragma unroll
    for (int i = 0; i < 4; ++i) {
      const int nl = n0 + 32 * i;
      const int sb = (erp >> 3) ^ ((nl >> 4) & 3);
      *(unsigned int*)(lB + nl * 40 + sb * 8 + (erp & 7)) =
          cvt_pk_bf16(pb[i], pb[4 + i]);
    }
    __syncthreads();  // lB visible
    if (s < 7) {      // next-step prefetch overlaps MFMA phase
      const int k2 = kk + 32;
      u16* nA = (s & 1) ? wA0 : wA1;
      gload_lds16(Ab + (long)ra * 256 + k2 + sc, nA);
      gload_lds16(Ab + (long)(ra + 128) * 256 + k2 + sc, nA + 128 * 32);
#pragma unroll
      for (int i = 0; i < 4; ++i) {
        pb[i]     = Xb[(long)(k2 + erp) * 4096 + n0 + 32 * i];
        pb[4 + i] = Xb[(long)(k2 + erp + 1) * 4096 + n0 + 32 * i];
      }
    }
    short8 af[4];
#pragma unroll
    for (int i = 0; i < 4; ++i)
      af[i] = *(const short8*)(curA + (wm + i * 16 + l16) * 32 + rqA);
#pragma unroll
    for (int j = 0; j < 4; ++j) {
      const int n = wn + j * 16 + l16;
      const int rb = quad ^ ((n >> 4) & 3);
      const short8 bf = *(const short8*)(lB + n * 40 + rb * 8);
#pragma unroll
      for (int i = 0; i < 4; ++i)
        acc[i][j] = __builtin_amdgcn_mfma_f32_16x16x32_bf16(af[i], bf, acc[i][j], 0, 0, 0);
    }
  }
  const long obase = (long)b * 1048576;
#pragma unroll
  for (int i = 0; i < 4; ++i) {
    const int mb = wm + i * 16 + quad * 4;
#pragma unroll
    for (int j = 0; j < 4; ++j) {
      const int n = tn * 128 + wn + j * 16 + l16;
#pragma unroll
      for (int r = 0; r < 4; ++r)
        out[obase + (long)(mb + r) * 4096 + n] = acc[i][j][r] + bb[b * 256 + mb + r];
    }
  }
}

// -- softmax pass3: combine 16 tile partials + write WT bf16 + bb[d]=WT·b1 --
__global__ __launch_bounds__(256) void softmax_pass3(
    const float* __restrict__ Lt, const float* __restrict__ S2, const float* __restrict__ S3,
    const float* __restrict__ b2, const float* __restrict__ b3,
    const float* __restrict__ bm, const float* __restrict__ bs,
    const float* __restrict__ b1, u16* __restrict__ WTh, float* __restrict__ bb) {
  __shared__ float ls2[256], lb2[256], lb1[256];
  __shared__ float sM, sInv;
  const int b = blockIdx.y, blk = blockIdx.x, t = threadIdx.x;
  if (t < 64) {  // combine 16 tile partials (wave 0 only)
    const float m = (t < 16) ? bm[b * 16 + t] : -3.4e38f;
    float s = (t < 16) ? bs[b * 16 + t] : 0.f;
    float M = m;
    for (int o = 32; o; o >>= 1) M = fmaxf(M, __shfl_xor(M, o));
    s *= __expf(m - M);
    for (int o = 32; o; o >>= 1) s += __shfl_xor(s, o);
    if (t == 0) { sM = M; sInv = 1.0f / s; }
  }
  ls2[t] = S2[b * 256 + t];
  lb2[t] = b2[t];
  lb1[t] = b1[t];
  __syncthreads();
  const float M = sM, inv = sInv;
  const int fw0 = blk * 2048 + t * 8;
  const int d = fw0 >> 8, a0 = fw0 & 255;
  const float c1 = b3[d];
  const float c0 = S3[b * 256 + d] + 4096.f * c1;
  const long base = (long)b * 65536 + fw0;
  float4 v0 = *(const float4*)(Lt + base);
  float4 v1 = *(const float4*)(Lt + base + 4);
  float v[8] = {v0.x, v0.y, v0.z, v0.w, v1.x, v1.y, v1.z, v1.w};
  union { u16 h[8]; uint4 q; } o;
  float bsum = 0.f;
#pragma unroll
  for (int i = 0; i < 8; ++i) {
    const float vv = v[i] + lb2[a0 + i] * c0 + c1 * ls2[a0 + i];
    const float w = __expf(vv - M) * inv;
    o.h[i] = f2b(w);
    bsum += w * lb1[a0 + i];
  }
  *(uint4*)(WTh + base) = o.q;
  // row d spans 32 consecutive threads
  for (int off = 16; off; off >>= 1) bsum += __shfl_xor(bsum, off);
  if ((t & 31) == 0) bb[b * 256 + d] = bsum;
}

extern "C" void kernel_launch(void* const* d_in, const int* in_sizes, int n_in,
                              void* d_out, int out_size, void* d_ws, size_t ws_size,
                              hipStream_t stream) {
  const float* x  = (const float*)d_in[0];
  const float* w1 = (const float*)d_in[1];
  const float* b1 = (const float*)d_in[2];
  const float* w2 = (const float*)d_in[3];
  const float* b2 = (const float*)d_in[4];
  const float* w3 = (const float*)d_in[5];
  const float* b3 = (const float*)d_in[6];
  float* out = (float*)d_out;

  char* ws = (char*)d_ws;
  size_t off = 0;
  auto alloc = [&](size_t bytes) {
    void* p = ws + off;
    off += (bytes + 255) & ~(size_t)255;
    return p;
  };
  float* Gp = (float*)alloc(16ull * 16 * 65536 * 4);   // 64 MiB split-K partials
  float* xsum = (float*)alloc(16 * 256 * 4);
  u16* Gh   = (u16*)alloc(16ull * 65536 * 2);
  u16* Gl   = (u16*)alloc(16ull * 65536 * 2);
  u16* T3h  = (u16*)alloc(16ull * 65536 * 2);
  u16* T3l  = (u16*)alloc(16ull * 65536 * 2);
  float* Lb = (float*)alloc(16ull * 65536 * 4);        // Lt[d][a]
  u16* WTh  = (u16*)alloc(16ull * 65536 * 2);
  u16* Mh   = (u16*)alloc(16ull * 65536 * 2);
  u16* W1Th = (u16*)alloc(65536 * 2);
  u16* W2h  = (u16*)alloc(65536 * 2);
  u16* W2l  = (u16*)alloc(65536 * 2);
  u16* W3h  = (u16*)alloc(65536 * 2);
  u16* W3l  = (u16*)alloc(65536 * 2);
  float* S2   = (float*)alloc(16 * 256 * 4);
  float* S3   = (float*)alloc(16 * 256 * 4);
  float* bmx  = (float*)alloc(16 * 16 * 4);
  float* bsx  = (float*)alloc(16 * 16 * 4);
  float* bb   = (float*)alloc(16 * 256 * 4);

  prep_w_kernel<<<577, 256, 0, stream>>>(w1, w2, w3, W1Th, W2h, W2l, W3h, W3l, xsum);

  // Gram partials: 16 batches x 16 splits x 2 m-halves (xsum fused, mh==0).
  gram_kernel<<<512, 512, 0, stream>>>(x, Gp, xsum);
  // fused split-K reduce (1024 blocks) + bias prep (16 blocks)
  reduce_bias_kernel<<<1040, 256, 0, stream>>>(Gp, Gh, Gl, w2, w3, xsum, S2, S3);

  // T3 = W3 * G (G symmetric -> TN ok). 64x64 tiles, 256 blocks.
  gemm_small<true, 1><<<dim3(16, 1, 16), 256, 0, stream>>>(
      W3h, W3l, Gh, Gl, 0, 65536, 65536, nullptr, T3h, T3l,
      nullptr, nullptr, nullptr, nullptr, nullptr, nullptr);
  // Lt = T3 * W2^T (raw) + fused softmax-pass1 stats (bm/bs per tile).
  gemm_small<true, 3><<<dim3(16, 1, 16), 256, 0, stream>>>(
      T3h, T3l, W2h, W2l, 65536, 0, 65536, Lb, nullptr, nullptr,
      S2, S3, b2, b3, bmx, bsx);

  // softmax: combine + write WT + fused bb
  softmax_pass3<<<dim3(32, 16), 256, 0, stream>>>(Lb, S2, S3, b2, b3, bmx, bsx,
                                                  b1, WTh, bb);

  // out-chain: Mh = WT*W1T (bf16), out = Mh*X^T + bb
  gemm_small<false, 2><<<dim3(16, 1, 16), 256, 0, stream>>>(
      WTh, nullptr, W1Th, nullptr, 65536, 0, 65536, nullptr, Mh, nullptr,
      nullptr, nullptr, nullptr, nullptr, nullptr, nullptr);
  gemm_out<<<dim3(32, 1, 16), 512, 0, stream>>>(Mh, x, bb, out);
}

// Round 10
// 214.005 us; speedup vs baseline: 1.4988x; 1.4988x over previous
//
#include <hip/hip_runtime.h>

// GlobalChannelAttention: B=16, C=256, H*W=4096
//
// Pipeline (TN-form GEMMs: C[M,N] = sum_k A[m][k]*B[n][k], K contiguous):
//   1. prep_w: w1 -> W1Th (bf16 transposed), w2/w3 -> hi/lo bf16, zero xsum
//   2. gram: G[b] = X X^T from raw x f32 (hi/lo in SEPARATE LDS slabs, 3
//      MFMAs hh+hl+lh). HALF-M blocks: grid 16b x 16splits x 2mhalf.
//   3. reduce_bias: sum 16 Gp partials -> Gh/Gl bf16 + bias S2/S3 (fused).
//      T3 = W3*G (G symmetric); Lt = T3*W2^T (EPI=3: epilogue computes
//      per-tile biased max/sumexp partials -> softmax pass1 eliminated).
//   4. softmax pass3: combine 16 tile partials + write WT bf16 + fused
//      bb[d] = sum_c WT[d][c]*b1[c].
//   5. Mh = WT*W1T (bf16); out = Mh*X^T + bb, 256x128 tiles, 512 thr.
//
// Precision: logit chain bf16 hi/lo x3 (err ~2^-17 rel); out chain plain bf16.
// R7: atomic-f32 Gram epilogue regressed (16-way same-address L2 contention).
// R8: k-interleaved hi/lo loses hi*lo cross terms -> accuracy fail.
// R9: 128-VGPR acc forced fragment rematerialization -> LDS-read bound.
// R10: separate xsum_kernel re-read 64MB of x -- folded back into gram.
// R11: gram 16 k-splits, 64KiB LDS XOR-swizzle, cvt_pk staging. 46->41us,
//     0 bank conflicts (verified R5).
// R12/R13: launch_bounds(512,4) = 4 BLOCKS/CU -> 64-VGPR cap -> spill.
// R14: (512,2): spill gone; lB-write conflicts found.
// R15: gemm_out gload_lds dbuf A + conflict-free lB; left top-5.
// R16: gemm_small full-panel LDS single-barrier; left top-5.
// R17/R18: pass1 fused into gemm#2 epilogue (-4us); gram k-stagger NEUTRAL.
// R19: REGRESSED 213->320. gram load-issue-after-stage8 extended p[] live
//     range across the barrier; gram sits EXACTLY at its 64-VGPR cap
//     (launch_bounds(512,4) = 4 blk/CU) -> spill: WRITE 66->328MB (~1KB/thr
//     scratch), FETCH 66->159MB, dur 41->140us. Premise also wrong: compiler
//     emits s_waitcnt vmcnt(0) before EVERY s_barrier, so plain loads cannot
//     stay in flight across __syncthreads -- only counted-vmcnt + raw
//     s_barrier schedules can.
// R20 (this round): clean revert of gram to the R8 k-loop (loads at loop
//     top; measured 40.5-42.6us, 0 conflicts, no spill). reduce_bias and
//     EPI=3 fusions kept (untouched by the regression). Lesson pinned:
//     gram's VGPR budget has ZERO slack; do not extend live ranges.

typedef unsigned short u16;
typedef __attribute__((ext_vector_type(8))) short short8;
typedef __attribute__((ext_vector_type(4))) float floatx4;

__device__ __forceinline__ u16 f2b(float f) {
  union { float f; unsigned int u; } v; v.f = f;
  unsigned int u = v.u;
  return (u16)((u + 0x7fffu + ((u >> 16) & 1u)) >> 16);  // RNE
}
__device__ __forceinline__ float b2f(u16 h) {
  union { unsigned int u; float f; } v; v.u = ((unsigned int)h) << 16;
  return v.f;
}
// HW packed f32->bf16 (RNE), lo -> bits[15:0], hi -> bits[31:16].
__device__ __forceinline__ unsigned int cvt_pk_bf16(float lo, float hi) {
  unsigned int r;
  asm("v_cvt_pk_bf16_f32 %0, %1, %2" : "=v"(r) : "v"(lo), "v"(hi));
  return r;
}
// async global->LDS, 16B per lane. LDS dest = wave-uniform base + lane*16.
__device__ __forceinline__ void gload_lds16(const u16* g, u16* l) {
  __builtin_amdgcn_global_load_lds(
      (const __attribute__((address_space(1))) unsigned int*)(const void*)g,
      (__attribute__((address_space(3))) unsigned int*)(void*)l, 16, 0, 0);
}

// ------- merged W prep: transpose w1 + split w2/w3 + zero xsum -------------
__global__ __launch_bounds__(256) void prep_w_kernel(
    const float* __restrict__ w1, const float* __restrict__ w2, const float* __restrict__ w3,
    u16* __restrict__ W1Th, u16* __restrict__ W2h, u16* __restrict__ W2l,
    u16* __restrict__ W3h, u16* __restrict__ W3l, float* __restrict__ xsum) {
  const int blk = blockIdx.x, t = threadIdx.x;
  if (blk == 576) {  // zero xsum (16*256 f32)
#pragma unroll
    for (int i = 0; i < 16; ++i) xsum[t + i * 256] = 0.f;
    return;
  }
  if (blk < 64) {  // W1Th[e][c] = w1[c][e]
    __shared__ float tile[32][33];
    const int e0 = (blk & 7) * 32, c0 = (blk >> 3) * 32;
    const int tx = t & 31, ty = t >> 5;
#pragma unroll
    for (int i = 0; i < 4; ++i)
      tile[ty + i * 8][tx] = w1[(c0 + ty + i * 8) * 256 + e0 + tx];
    __syncthreads();
#pragma unroll
    for (int i = 0; i < 4; ++i)
      W1Th[(e0 + ty + i * 8) * 256 + c0 + tx] = f2b(tile[tx][ty + i * 8]);
  } else {
    const int i = (blk - 64) * 256 + t;  // 0..131071
    const int e = i & 0xffff;
    const float f = (i >> 16) ? w3[e] : w2[e];
    u16 h = f2b(f);
    if (i >> 16) { W3h[e] = h; W3l[e] = f2b(f - b2f(h)); }
    else         { W2h[e] = h; W2l[e] = f2b(f - b2f(h)); }
  }
}

// ---- stage 8 f32 -> hi/lo bf16 LDS (one uint4 each) + running sum --------
__device__ __forceinline__ void stage8(const float4 a, const float4 b,
                                       u16* dH, u16* dL, float& xa) {
  const float f[8] = {a.x, a.y, a.z, a.w, b.x, b.y, b.z, b.w};
  union { unsigned int w[4]; uint4 q; } uh, ul;
#pragma unroll
  for (int i = 0; i < 4; ++i) {
    const unsigned int h = cvt_pk_bf16(f[2 * i], f[2 * i + 1]);
    uh.w[i] = h;
    union { unsigned int u; float ff; } h0, h1;
    h0.u = h << 16;            // bf16 of f[2i] back to f32
    h1.u = h & 0xffff0000u;    // bf16 of f[2i+1] back to f32
    ul.w[i] = cvt_pk_bf16(f[2 * i] - h0.ff, f[2 * i + 1] - h1.ff);
    xa += f[2 * i] + f[2 * i + 1];
  }
  *(uint4*)dH = uh.q;
  *(uint4*)dL = ul.q;
}

// ---------------- Gram: half-M blocks, hoisted fragments -------------------
// grid = 16b x 16s x 2mh. 512 thr / 8 waves, wave tile 64x64, k-chunk 256.
// LDS: row r = 64B = 4x16B slots; slot q ^ ((r>>1)&3); both phases bank-free
// (measured 0 conflicts). 64 KiB -> 2 blocks/CU. R8 structure: loads issued
// at loop TOP (covered by the MFMA phase), consumed by stage8 before the
// barrier -- p[] live range stays within one iteration (64-VGPR cap has
// zero slack; R19's cross-barrier extension spilled).
__global__ __launch_bounds__(512, 4) void gram_kernel(
    const float* __restrict__ x, float* __restrict__ Gp, float* __restrict__ xsum) {
  __shared__ u16 lH[2][256 * 32], lL[2][256 * 32];  // 64 KB total
  const int b = blockIdx.x >> 5, s = (blockIdx.x >> 1) & 15, mh = blockIdx.x & 1;
  const float* Xb = x + (long)b * 1048576 + s * 256;
  const int t = threadIdx.x;
  const int lane = t & 63, wave = t >> 6;
  const int quad = lane >> 4, l16 = lane & 15;
  const int wml = (wave & 1) * 64 + mh * 128;  // A rows in slab
  const int wn = (wave >> 1) * 64;             // B rows
  const int r0 = t >> 2, qc = (t & 3) * 8;
  const int r1 = r0 + 128;                     // (r1>>1)&3 == (r0>>1)&3
  const int wq = (((t & 3) ^ ((r0 >> 1) & 3))) * 8;  // swizzled write slot
  const int rq = ((quad ^ ((l16 >> 1) & 3))) * 8;    // swizzled read slot
  const int ph = s & 7;  // k-step phase stagger (neutral, harmless)
  floatx4 acc[4][4] = {};
  float xa0 = 0.f, xa1 = 0.f;  // per-row running sums (rows r0, r1)
  float4 p[4];
  {
    const long k0 = (long)(ph * 32);
    p[0] = *(const float4*)(Xb + (long)r0 * 4096 + k0 + qc);
    p[1] = *(const float4*)(Xb + (long)r0 * 4096 + k0 + qc + 4);
    p[2] = *(const float4*)(Xb + (long)r1 * 4096 + k0 + qc);
    p[3] = *(const float4*)(Xb + (long)r1 * 4096 + k0 + qc + 4);
  }
  stage8(p[0], p[1], lH[0] + r0 * 32 + wq, lL[0] + r0 * 32 + wq, xa0);
  stage8(p[2], p[3], lH[0] + r1 * 32 + wq, lL[0] + r1 * 32 + wq, xa1);
  __syncthreads();
  for (int kb = 0; kb < 8; ++kb) {
    const int cur = kb & 1, nxt = cur ^ 1;
    if (kb < 7) {  // issue next tile's loads; waitcnt lands after MFMA block
      const long kk = (long)(((kb + 1 + ph) & 7) * 32);
      p[0] = *(const float4*)(Xb + (long)r0 * 4096 + kk + qc);
      p[1] = *(const float4*)(Xb + (long)r0 * 4096 + kk + qc + 4);
      p[2] = *(const float4*)(Xb + (long)r1 * 4096 + kk + qc);
      p[3] = *(const float4*)(Xb + (long)r1 * 4096 + kk + qc + 4);
    }
    const u16* cH = lH[cur];
    const u16* cL = lL[cur];
    short8 ah[4], al[4];
#pragma unroll
    for (int i = 0; i < 4; ++i) {
      ah[i] = *(const short8*)(cH + (wml + i * 16 + l16) * 32 + rq);
      al[i] = *(const short8*)(cL + (wml + i * 16 + l16) * 32 + rq);
    }
#pragma unroll
    for (int j = 0; j < 4; ++j) {
      const short8 bh = *(const short8*)(cH + (wn + j * 16 + l16) * 32 + rq);
      const short8 bl = *(const short8*)(cL + (wn + j * 16 + l16) * 32 + rq);
#pragma unroll
      for (int i = 0; i < 4; ++i) {
        acc[i][j] = __builtin_amdgcn_mfma_f32_16x16x32_bf16(ah[i], bh, acc[i][j], 0, 0, 0);
        acc[i][j] = __builtin_amdgcn_mfma_f32_16x16x32_bf16(ah[i], bl, acc[i][j], 0, 0, 0);
        acc[i][j] = __builtin_amdgcn_mfma_f32_16x16x32_bf16(al[i], bh, acc[i][j], 0, 0, 0);
      }
    }
    if (kb < 7) {
      stage8(p[0], p[1], lH[nxt] + r0 * 32 + wq, lL[nxt] + r0 * 32 + wq, xa0);
      stage8(p[2], p[3], lH[nxt] + r1 * 32 + wq, lL[nxt] + r1 * 32 + wq, xa1);
    }
    __syncthreads();
  }
  if (mh == 0) {
    float v = xa0;
    v += __shfl_xor(v, 1);
    v += __shfl_xor(v, 2);
    if ((t & 3) == 0) atomicAdd(&xsum[b * 256 + r0], v);
    v = xa1;
    v += __shfl_xor(v, 1);
    v += __shfl_xor(v, 2);
    if ((t & 3) == 0) atomicAdd(&xsum[b * 256 + r1], v);
  }
  float* G = Gp + ((long)b * 16 + s) * 65536;
#pragma unroll
  for (int i = 0; i < 4; ++i) {
    const int row0 = wml + i * 16 + quad * 4;
#pragma unroll
    for (int j = 0; j < 4; ++j) {
      const int col = wn + j * 16 + l16;
#pragma unroll
      for (int r = 0; r < 4; ++r)
        G[(long)(row0 + r) * 256 + col] = acc[i][j][r];
    }
  }
}

// -- fused: Gram split-K reduction (blocks 0..1023) + bias prep (1024..1039)
// reduce: 4 consecutive elems/thread, same i=0..15 order (bitwise-identical).
// bias: S2[b][a]=w2[a,:]·xsum[b], S3 likewise (one block per batch).
__global__ __launch_bounds__(256) void reduce_bias_kernel(
    const float* __restrict__ Gp, u16* __restrict__ Gh, u16* __restrict__ Gl,
    const float* __restrict__ w2, const float* __restrict__ w3,
    const float* __restrict__ xsum, float* __restrict__ S2, float* __restrict__ S3) {
  __shared__ float xs[256];
  const int t = threadIdx.x;
  if (blockIdx.x < 1024) {
    const long e = ((long)blockIdx.x * 256 + t) * 4;    // elem base
    const long base = ((e >> 16) << 20) + (e & 65535);  // b*16*65536 + idx
    float4 s = {0.f, 0.f, 0.f, 0.f};
#pragma unroll
    for (int i = 0; i < 16; ++i) {
      const float4 v = *(const float4*)(Gp + base + (long)i * 65536);
      s.x += v.x; s.y += v.y; s.z += v.z; s.w += v.w;
    }
    union { u16 h[4]; uint2 q; } oh, ol;
    const float sv[4] = {s.x, s.y, s.z, s.w};
#pragma unroll
    for (int c = 0; c < 4; ++c) {
      const u16 h = f2b(sv[c]);
      oh.h[c] = h;
      ol.h[c] = f2b(sv[c] - b2f(h));
    }
    *(uint2*)(Gh + e) = oh.q;
    *(uint2*)(Gl + e) = ol.q;
  } else {
    const int b = blockIdx.x - 1024;
    xs[t] = xsum[b * 256 + t];
    __syncthreads();
    float s2 = 0.f, s3 = 0.f;
#pragma unroll 4
    for (int c = 0; c < 256; ++c) {
      s2 += w2[t * 256 + c] * xs[c];
      s3 += w3[t * 256 + c] * xs[c];
    }
    S2[b * 256 + t] = s2;
    S3[b * 256 + t] = s3;
  }
}

// ------- small 256x256x256 TN GEMM: full-panel LDS, 64x64 tiles ------------
// Full A(64x256) + B(64x256) hi(/lo) panels staged ONCE into padded LDS
// ([64][264] u16, 528B row stride -> conflict-free), one barrier, then 8
// barrier-free k-steps. Grid 256 = 1 block/CU. EPI: 0=f32, 1=bf16 hi/lo,
// 2=bf16 hi, 3=f32 + fused softmax-pass1 stats (biased per-tile max/sumexp
// -> bm/bs[b*16+blk]; raw value still stored to outF).
template <bool X3, int EPI>
__global__ __launch_bounds__(256) void gemm_small(
    const u16* __restrict__ Ah, const u16* __restrict__ Al,
    const u16* __restrict__ Bh, const u16* __restrict__ Bl,
    long aBatch, long bBatch, long oBatch,
    float* __restrict__ outF, u16* __restrict__ outH, u16* __restrict__ outL,
    const float* __restrict__ S2, const float* __restrict__ S3,
    const float* __restrict__ b2v, const float* __restrict__ b3v,
    float* __restrict__ bm, float* __restrict__ bs) {
  constexpr int LW = 264;  // row stride in elems (528 B)
  __shared__ u16 smem[(X3 ? 4 : 2) * 64 * LW];
  __shared__ float rm[4], rs[4];  // EPI3 block-reduce scratch
  u16* lAh = smem;
  u16* lBh = smem + 64 * LW;
  u16* lAl = X3 ? (smem + 2 * 64 * LW) : nullptr;
  u16* lBl = X3 ? (smem + 3 * 64 * LW) : nullptr;
  const int b = blockIdx.z;
  const int tm = blockIdx.x & 3, tn = blockIdx.x >> 2;  // 4x4 tiles of 64
  const u16* Ahb = Ah + (long)b * aBatch + (long)tm * 64 * 256;
  const u16* Bhb = Bh + (long)b * bBatch + (long)tn * 64 * 256;
  const int t = threadIdx.x;
  const int lane = t & 63, wave = t >> 6;
  const int quad = lane >> 4, l16 = lane & 15;
  const int wm = (wave & 1) * 32, wn = (wave >> 1) * 32;
  const int r = t >> 2, c4 = t & 3;  // staging: row r, slots c4+4j (16B each)
  {
    uint4 tmp[8];
#pragma unroll
    for (int j = 0; j < 8; ++j)
      tmp[j] = *(const uint4*)(Ahb + (long)r * 256 + (c4 + 4 * j) * 8);
#pragma unroll
    for (int j = 0; j < 8; ++j)
      *(uint4*)(lAh + r * LW + (c4 + 4 * j) * 8) = tmp[j];
#pragma unroll
    for (int j = 0; j < 8; ++j)
      tmp[j] = *(const uint4*)(Bhb + (long)r * 256 + (c4 + 4 * j) * 8);
#pragma unroll
    for (int j = 0; j < 8; ++j)
      *(uint4*)(lBh + r * LW + (c4 + 4 * j) * 8) = tmp[j];
    if (X3) {
      const u16* Alb = Al + (long)b * aBatch + (long)tm * 64 * 256;
      const u16* Blb = Bl + (long)b * bBatch + (long)tn * 64 * 256;
#pragma unroll
      for (int j = 0; j < 8; ++j)
        tmp[j] = *(const uint4*)(Alb + (long)r * 256 + (c4 + 4 * j) * 8);
#pragma unroll
      for (int j = 0; j < 8; ++j)
        *(uint4*)(lAl + r * LW + (c4 + 4 * j) * 8) = tmp[j];
#pragma unroll
      for (int j = 0; j < 8; ++j)
        tmp[j] = *(const uint4*)(Blb + (long)r * 256 + (c4 + 4 * j) * 8);
#pragma unroll
      for (int j = 0; j < 8; ++j)
        *(uint4*)(lBl + r * LW + (c4 + 4 * j) * 8) = tmp[j];
    }
  }
  __syncthreads();  // the ONLY barrier in the GEMM body
  floatx4 acc[2][2] = {};
#pragma unroll
  for (int kk = 0; kk < 8; ++kk) {
    const int co = kk * 32 + quad * 8;
    short8 afh[2], bfh[2];
#pragma unroll
    for (int i = 0; i < 2; ++i) {
      afh[i] = *(const short8*)(lAh + (wm + i * 16 + l16) * LW + co);
      bfh[i] = *(const short8*)(lBh + (wn + i * 16 + l16) * LW + co);
    }
    if (X3) {
      short8 afl[2], bfl[2];
#pragma unroll
      for (int i = 0; i < 2; ++i) {
        afl[i] = *(const short8*)(lAl + (wm + i * 16 + l16) * LW + co);
        bfl[i] = *(const short8*)(lBl + (wn + i * 16 + l16) * LW + co);
      }
#pragma unroll
      for (int i = 0; i < 2; ++i)
#pragma unroll
        for (int j = 0; j < 2; ++j) {
          acc[i][j] = __builtin_amdgcn_mfma_f32_16x16x32_bf16(afh[i], bfh[j], acc[i][j], 0, 0, 0);
          acc[i][j] = __builtin_amdgcn_mfma_f32_16x16x32_bf16(afh[i], bfl[j], acc[i][j], 0, 0, 0);
          acc[i][j] = __builtin_amdgcn_mfma_f32_16x16x32_bf16(afl[i], bfh[j], acc[i][j], 0, 0, 0);
        }
    } else {
#pragma unroll
      for (int i = 0; i < 2; ++i)
#pragma unroll
        for (int j = 0; j < 2; ++j)
          acc[i][j] = __builtin_amdgcn_mfma_f32_16x16x32_bf16(afh[i], bfh[j], acc[i][j], 0, 0, 0);
    }
  }
  const long obase = (long)b * oBatch;
  if (EPI == 3) {
    // store raw Lt + fused pass1 stats on biased values
    float vals[2][2][4];
    float vmax = -3.4e38f;
#pragma unroll
    for (int i = 0; i < 2; ++i) {
      const int mb = tm * 64 + wm + i * 16 + quad * 4;
#pragma unroll
      for (int rr = 0; rr < 4; ++rr) {
        const int d = mb + rr;
        const float c1 = b3v[d];
        const float c0 = S3[b * 256 + d] + 4096.f * c1;
#pragma unroll
        for (int j = 0; j < 2; ++j) {
          const int a = tn * 64 + wn + j * 16 + l16;
          const float raw = acc[i][j][rr];
          const float vv = raw + b2v[a] * c0 + c1 * S2[b * 256 + a];
          vals[i][j][rr] = vv;
          vmax = fmaxf(vmax, vv);
          outF[obase + (long)d * 256 + a] = raw;
        }
      }
    }
    for (int o = 32; o; o >>= 1) vmax = fmaxf(vmax, __shfl_xor(vmax, o));
    if (lane == 0) rm[wave] = vmax;
    __syncthreads();
    const float bmax = fmaxf(fmaxf(rm[0], rm[1]), fmaxf(rm[2], rm[3]));
    float se = 0.f;
#pragma unroll
    for (int i = 0; i < 2; ++i)
#pragma unroll
      for (int j = 0; j < 2; ++j)
#pragma unroll
        for (int rr = 0; rr < 4; ++rr) se += __expf(vals[i][j][rr] - bmax);
    for (int o = 32; o; o >>= 1) se += __shfl_xor(se, o);
    if (lane == 0) rs[wave] = se;
    __syncthreads();
    if (t == 0) {
      bm[b * 16 + blockIdx.x] = bmax;
      bs[b * 16 + blockIdx.x] = rs[0] + rs[1] + rs[2] + rs[3];
    }
    return;
  }
#pragma unroll
  for (int i = 0; i < 2; ++i) {
    const int mb = tm * 64 + wm + i * 16 + quad * 4;
#pragma unroll
    for (int j = 0; j < 2; ++j) {
      const int n = tn * 64 + wn + j * 16 + l16;
#pragma unroll
      for (int rr = 0; rr < 4; ++rr) {
        const float v = acc[i][j][rr];
        const long idx = obase + (long)(mb + rr) * 256 + n;
        if (EPI == 0) {
          outF[idx] = v;
        } else if (EPI == 1) {
          u16 h = f2b(v);
          outH[idx] = h;
          outL[idx] = f2b(v - b2f(h));
        } else {
          outH[idx] = f2b(v);
        }
      }
    }
  }
}

// ------------- out = Mh * X^T + bb : 256x128 per block, 8 waves ------------
// A (Mh bf16): global_load_lds width-16, double-buffered, rows 64B (LR=32),
// XOR slot q^((r>>1)&3) applied to per-lane GLOBAL source col + read slot.
// B (x f32): 8 coalesced scalar dwords, cvt_pk pair-pack into lB (LR=40);
// lane t writes nl=(t&31)+32i (write phase conflict-free).
__global__ __launch_bounds__(512, 2) void gemm_out(
    const u16* __restrict__ Mh, const float* __restrict__ x,
    const float* __restrict__ bb, float* __restrict__ out) {
  __shared__ u16 lA[2][256 * 32];  // 2 x 16 KB
  __shared__ u16 lB[128 * 40];     // 10 KB
  const int b = blockIdx.z;
  const int tn = blockIdx.x;  // 0..31
  const u16* Ab = Mh + (long)b * 65536;
  const float* Xb = x + (long)b * 1048576 + tn * 128;
  const int t = threadIdx.x;
  const int lane = t & 63, wave = t >> 6;
  const int quad = lane >> 4, l16 = lane & 15;
  const int wm = (wave & 3) * 64;     // 4 m-waves
  const int wn = (wave >> 2) * 64;    // 2 n-waves
  const int erp = (t >> 5) * 2;       // e-row pair base 0..30
  const int n0 = t & 31;              // B col base (cols n0+32i)
  const int ra = t >> 2;              // A row
  const int sc = ((t & 3) ^ ((t >> 3) & 3)) * 8;   // pre-swizzled A src col
  const int rqA = (quad ^ ((l16 >> 1) & 3)) * 8;   // A read slot
  u16* wA0 = &lA[0][0] + wave * 16 * 32;           // wave-uniform LDS bases
  u16* wA1 = &lA[1][0] + wave * 16 * 32;
  floatx4 acc[4][4] = {};
  float pb[8];
  gload_lds16(Ab + (long)ra * 256 + sc, wA0);
  gload_lds16(Ab + (long)(ra + 128) * 256 + sc, wA0 + 128 * 32);
#pragma unroll
  for (int i = 0; i < 4; ++i) {
    pb[i]     = Xb[(long)erp * 4096 + n0 + 32 * i];
    pb[4 + i] = Xb[(long)(erp + 1) * 4096 + n0 + 32 * i];
  }
  for (int s = 0; s < 8; ++s) {
    const int kk = s * 32;
    const u16* curA = lA[s & 1];
    __syncthreads();  // drains gloads into buf[s&1] + pb loads (vmcnt 0)
#pragma unroll
    for (int i = 0; i < 4; ++i) {
      const int nl = n0 + 32 * i;
      const int sb = (erp >> 3) ^ ((nl >> 4) & 3);
      *(unsigned int*)(lB + nl * 40 + sb * 8 + (erp & 7)) =
          cvt_pk_bf16(pb[i], pb[4 + i]);
    }
    __syncthreads();  // lB visible
    if (s < 7) {      // next-step prefetch overlaps MFMA phase
      const int k2 = kk + 32;
      u16* nA = (s & 1) ? wA0 : wA1;
      gload_lds16(Ab + (long)ra * 256 + k2 + sc, nA);
      gload_lds16(Ab + (long)(ra + 128) * 256 + k2 + sc, nA + 128 * 32);
#pragma unroll
      for (int i = 0; i < 4; ++i) {
        pb[i]     = Xb[(long)(k2 + erp) * 4096 + n0 + 32 * i];
        pb[4 + i] = Xb[(long)(k2 + erp + 1) * 4096 + n0 + 32 * i];
      }
    }
    short8 af[4];
#pragma unroll
    for (int i = 0; i < 4; ++i)
      af[i] = *(const short8*)(curA + (wm + i * 16 + l16) * 32 + rqA);
#pragma unroll
    for (int j = 0; j < 4; ++j) {
      const int n = wn + j * 16 + l16;
      const int rb = quad ^ ((n >> 4) & 3);
      const short8 bf = *(const short8*)(lB + n * 40 + rb * 8);
#pragma unroll
      for (int i = 0; i < 4; ++i)
        acc[i][j] = __builtin_amdgcn_mfma_f32_16x16x32_bf16(af[i], bf, acc[i][j], 0, 0, 0);
    }
  }
  const long obase = (long)b * 1048576;
#pragma unroll
  for (int i = 0; i < 4; ++i) {
    const int mb = wm + i * 16 + quad * 4;
#pragma unroll
    for (int j = 0; j < 4; ++j) {
      const int n = tn * 128 + wn + j * 16 + l16;
#pragma unroll
      for (int r = 0; r < 4; ++r)
        out[obase + (long)(mb + r) * 4096 + n] = acc[i][j][r] + bb[b * 256 + mb + r];
    }
  }
}

// -- softmax pass3: combine 16 tile partials + write WT bf16 + bb[d]=WT·b1 --
__global__ __launch_bounds__(256) void softmax_pass3(
    const float* __restrict__ Lt, const float* __restrict__ S2, const float* __restrict__ S3,
    const float* __restrict__ b2, const float* __restrict__ b3,
    const float* __restrict__ bm, const float* __restrict__ bs,
    const float* __restrict__ b1, u16* __restrict__ WTh, float* __restrict__ bb) {
  __shared__ float ls2[256], lb2[256], lb1[256];
  __shared__ float sM, sInv;
  const int b = blockIdx.y, blk = blockIdx.x, t = threadIdx.x;
  if (t < 64) {  // combine 16 tile partials (wave 0 only)
    const float m = (t < 16) ? bm[b * 16 + t] : -3.4e38f;
    float s = (t < 16) ? bs[b * 16 + t] : 0.f;
    float M = m;
    for (int o = 32; o; o >>= 1) M = fmaxf(M, __shfl_xor(M, o));
    s *= __expf(m - M);
    for (int o = 32; o; o >>= 1) s += __shfl_xor(s, o);
    if (t == 0) { sM = M; sInv = 1.0f / s; }
  }
  ls2[t] = S2[b * 256 + t];
  lb2[t] = b2[t];
  lb1[t] = b1[t];
  __syncthreads();
  const float M = sM, inv = sInv;
  const int fw0 = blk * 2048 + t * 8;
  const int d = fw0 >> 8, a0 = fw0 & 255;
  const float c1 = b3[d];
  const float c0 = S3[b * 256 + d] + 4096.f * c1;
  const long base = (long)b * 65536 + fw0;
  float4 v0 = *(const float4*)(Lt + base);
  float4 v1 = *(const float4*)(Lt + base + 4);
  float v[8] = {v0.x, v0.y, v0.z, v0.w, v1.x, v1.y, v1.z, v1.w};
  union { u16 h[8]; uint4 q; } o;
  float bsum = 0.f;
#pragma unroll
  for (int i = 0; i < 8; ++i) {
    const float vv = v[i] + lb2[a0 + i] * c0 + c1 * ls2[a0 + i];
    const float w = __expf(vv - M) * inv;
    o.h[i] = f2b(w);
    bsum += w * lb1[a0 + i];
  }
  *(uint4*)(WTh + base) = o.q;
  // row d spans 32 consecutive threads
  for (int off = 16; off; off >>= 1) bsum += __shfl_xor(bsum, off);
  if ((t & 31) == 0) bb[b * 256 + d] = bsum;
}

extern "C" void kernel_launch(void* const* d_in, const int* in_sizes, int n_in,
                              void* d_out, int out_size, void* d_ws, size_t ws_size,
                              hipStream_t stream) {
  const float* x  = (const float*)d_in[0];
  const float* w1 = (const float*)d_in[1];
  const float* b1 = (const float*)d_in[2];
  const float* w2 = (const float*)d_in[3];
  const float* b2 = (const float*)d_in[4];
  const float* w3 = (const float*)d_in[5];
  const float* b3 = (const float*)d_in[6];
  float* out = (float*)d_out;

  char* ws = (char*)d_ws;
  size_t off = 0;
  auto alloc = [&](size_t bytes) {
    void* p = ws + off;
    off += (bytes + 255) & ~(size_t)255;
    return p;
  };
  float* Gp = (float*)alloc(16ull * 16 * 65536 * 4);   // 64 MiB split-K partials
  float* xsum = (float*)alloc(16 * 256 * 4);
  u16* Gh   = (u16*)alloc(16ull * 65536 * 2);
  u16* Gl   = (u16*)alloc(16ull * 65536 * 2);
  u16* T3h  = (u16*)alloc(16ull * 65536 * 2);
  u16* T3l  = (u16*)alloc(16ull * 65536 * 2);
  float* Lb = (float*)alloc(16ull * 65536 * 4);        // Lt[d][a]
  u16* WTh  = (u16*)alloc(16ull * 65536 * 2);
  u16* Mh   = (u16*)alloc(16ull * 65536 * 2);
  u16* W1Th = (u16*)alloc(65536 * 2);
  u16* W2h  = (u16*)alloc(65536 * 2);
  u16* W2l  = (u16*)alloc(65536 * 2);
  u16* W3h  = (u16*)alloc(65536 * 2);
  u16* W3l  = (u16*)alloc(65536 * 2);
  float* S2   = (float*)alloc(16 * 256 * 4);
  float* S3   = (float*)alloc(16 * 256 * 4);
  float* bmx  = (float*)alloc(16 * 16 * 4);
  float* bsx  = (float*)alloc(16 * 16 * 4);
  float* bb   = (float*)alloc(16 * 256 * 4);

  prep_w_kernel<<<577, 256, 0, stream>>>(w1, w2, w3, W1Th, W2h, W2l, W3h, W3l, xsum);

  // Gram partials: 16 batches x 16 splits x 2 m-halves (xsum fused, mh==0).
  gram_kernel<<<512, 512, 0, stream>>>(x, Gp, xsum);
  // fused split-K reduce (1024 blocks) + bias prep (16 blocks)
  reduce_bias_kernel<<<1040, 256, 0, stream>>>(Gp, Gh, Gl, w2, w3, xsum, S2, S3);

  // T3 = W3 * G (G symmetric -> TN ok). 64x64 tiles, 256 blocks.
  gemm_small<true, 1><<<dim3(16, 1, 16), 256, 0, stream>>>(
      W3h, W3l, Gh, Gl, 0, 65536, 65536, nullptr, T3h, T3l,
      nullptr, nullptr, nullptr, nullptr, nullptr, nullptr);
  // Lt = T3 * W2^T (raw) + fused softmax-pass1 stats (bm/bs per tile).
  gemm_small<true, 3><<<dim3(16, 1, 16), 256, 0, stream>>>(
      T3h, T3l, W2h, W2l, 65536, 0, 65536, Lb, nullptr, nullptr,
      S2, S3, b2, b3, bmx, bsx);

  // softmax: combine + write WT + fused bb
  softmax_pass3<<<dim3(32, 16), 256, 0, stream>>>(Lb, S2, S3, b2, b3, bmx, bsx,
                                                  b1, WTh, bb);

  // out-chain: Mh = WT*W1T (bf16), out = Mh*X^T + bb
  gemm_small<false, 2><<<dim3(16, 1, 16), 256, 0, stream>>>(
      WTh, nullptr, W1Th, nullptr, 65536, 0, 65536, nullptr, Mh, nullptr,
      nullptr, nullptr, nullptr, nullptr, nullptr, nullptr);
  gemm_out<<<dim3(32, 1, 16), 512, 0, stream>>>(Mh, x, bb, out);
}